// Round 1
// baseline (746.536 us; speedup 1.0000x reference)
//
#include <hip/hip_runtime.h>
#include <math.h>

#define NCL 10
#define DM 512
#define NH 8
#define DK 64
#define NB 8
#define SL 2048
#define LK 228
#define UF 100
#define KP_PER_B (NH*LK*DK)     // 116736
#define KP_TOT (NB*KP_PER_B)    // 933888
#define NROWS (NB*LK*UF)        // 182400

__device__ __forceinline__ float gelu_f(float x) {
    return 0.5f * x * (1.f + erff(x * 0.70710678118654752f));
}

// ---------------- kernel 0: zero accumulators ----------------
__global__ void k_init(float* __restrict__ acc) {
    if (threadIdx.x < 4) acc[threadIdx.x] = 0.f;
}

// ---------------- kernel 1: max-pool K and V ----------------
__global__ void k_pool(const float* __restrict__ K, const float* __restrict__ V,
                       float* __restrict__ Kp, float* __restrict__ Vp) {
    int idx = blockIdx.x * 256 + threadIdx.x;
    if (idx >= 2 * KP_TOT) return;
    const float* src = (idx < KP_TOT) ? K : V;
    float* dst = (idx < KP_TOT) ? Kp : Vp;
    int e = (idx < KP_TOT) ? idx : idx - KP_TOT;
    int b   = e / KP_PER_B;
    int off = e % KP_PER_B;
    int c  = off / LK;        // channel 0..511
    int pp = off % LK;        // pooled position 0..227
    int p0 = pp * 9 - 4;
    const float* base = src + (size_t)b * 1048576 + (size_t)c * 2048;
    float mx = -3.4e38f;
    #pragma unroll
    for (int j = 0; j < 9; ++j) {
        int p = p0 + j;
        if (p >= 0 && p < 2048) mx = fmaxf(mx, base[p]);
    }
    dst[e] = mx;
}

// ---------------- kernel 2: q-MLP + softmax + stats + centers ----------------
// one block per (b,l) pair; owns all 100 u-rows.
__global__ __launch_bounds__(256) void k_mlp(
        const float* __restrict__ Kp,
        const float* __restrict__ Wq1, const float* __restrict__ bq1,
        const float* __restrict__ Wq2, const float* __restrict__ bq2,
        float* __restrict__ mu_g, float* __restrict__ centers_g,
        float* __restrict__ acc_g) {
    __shared__ alignas(16) float Sst[512 * 8];   // staged Kp values per run (slots 1..7)
    __shared__ alignas(16) float xT[64 * 100];   // k-chunk transposed input tile
    __shared__ alignas(16) float hT[100 * 40];   // hidden outputs
    __shared__ float total_l[NCL];
    __shared__ float S_l[NCL * NCL];
    __shared__ float lp_acc;

    int tid = threadIdx.x;
    int bl = blockIdx.x;          // 0..1823
    int b = bl / LK;
    int l = bl % LK;

    // stage the <=7 nonzero Kp values per run (512 runs)
    for (int s = tid; s < 512 * 7; s += 256) {
        int rl = s / 7;
        int bk = s % 7 + 1;                 // source batch 1..7
        int rg = l * 512 + rl;              // global run index (per batch)
        int hh = rg / 14592;
        int rh = rg % 14592;
        int lp_ = rh >> 6;
        int dd = rh & 63;
        Sst[rl * 8 + bk] = Kp[((bk * NH + hh) * LK + lp_) * DK + dd];
    }
    if (tid < NCL) total_l[tid] = 0.f;
    if (tid < NCL * NCL) S_l[tid] = 0.f;
    if (tid == 0) lp_acc = 0.f;
    __syncthreads();

    int hg = tid & 7;     // hidden group: j = hg*5 .. hg*5+4
    int rg = tid >> 3;    // row group: rows rg*4 .. rg*4+3
    bool active = (rg < 25);
    float accv[4][5];
    #pragma unroll
    for (int a = 0; a < 4; ++a)
        #pragma unroll
        for (int c = 0; c < 5; ++c) accv[a][c] = 0.f;

    for (int kc = 0; kc < 512; kc += 64) {
        // stage xT[i][r] = K_unf input value at column kc+i of row (b,l,r)
        for (int s = tid; s < 64 * 100; s += 256) {
            int i = s / 100;
            int r = s % 100;
            int local = r * 512 + kc + i;      // 0..51199
            int rl = local / 100;
            int u = local % 100;
            int j = b + u;
            xT[i * 100 + r] = (j < 100) ? 0.f : Sst[rl * 8 + (j - 99)];
        }
        __syncthreads();
        if (active) {
            #pragma unroll 8
            for (int i = 0; i < 64; ++i) {
                float4 xv = *(const float4*)&xT[i * 100 + rg * 4];
                int wb = (kc + i) * 40 + hg * 5;
                #pragma unroll
                for (int c = 0; c < 5; ++c) {
                    float w = Wq1[wb + c];
                    accv[0][c] = fmaf(xv.x, w, accv[0][c]);
                    accv[1][c] = fmaf(xv.y, w, accv[1][c]);
                    accv[2][c] = fmaf(xv.z, w, accv[2][c]);
                    accv[3][c] = fmaf(xv.w, w, accv[3][c]);
                }
            }
        }
        __syncthreads();
    }

    if (active) {
        #pragma unroll
        for (int a = 0; a < 4; ++a) {
            int row = rg * 4 + a;
            #pragma unroll
            for (int c = 0; c < 5; ++c) {
                int j = hg * 5 + c;
                hT[row * 40 + j] = accv[a][c] + bq1[j];
            }
        }
    }
    __syncthreads();

    if (tid < 100) {
        int row = tid;
        float g[40];
        #pragma unroll
        for (int j = 0; j < 40; ++j)
            g[j] = gelu_f(hT[row * 40 + j]);
        float out[10];
        #pragma unroll
        for (int c = 0; c < 10; ++c) out[c] = bq2[c];
        #pragma unroll
        for (int j = 0; j < 40; ++j) {
            float gj = g[j];
            #pragma unroll
            for (int c = 0; c < 10; ++c)
                out[c] = fmaf(gj, Wq2[j * 10 + c], out[c]);
        }
        // softmax + first-occurrence argmax
        float m = out[0]; int am = 0;
        #pragma unroll
        for (int c = 1; c < 10; ++c)
            if (out[c] > m) { m = out[c]; am = c; }
        float e[10], s = 0.f;
        #pragma unroll
        for (int c = 0; c < 10; ++c) { e[c] = expf(out[c] - m); s += e[c]; }
        float inv = 1.f / s;
        float cq[10], s1 = 0.f;
        #pragma unroll
        for (int c = 0; c < 10; ++c) { cq[c] = e[c] * inv; s1 += cq[c]; }
        float mean = s1 * 0.1f;
        float var = 0.f;
        #pragma unroll
        for (int c = 0; c < 10; ++c) { float d = cq[c] - mean; var += d * d; }
        float sd = sqrtf(var / 9.f);
        float sp = log1pf(expf(sd));             // softplus(std)
        float lp = -logf(sp) - 0.91893853320467274f;  // ((x-mu)/sigma)^2 ~ 1e-16, dropped
        mu_g[bl * 100 + row] = mean;
        atomicAdd(&lp_acc, lp);
        #pragma unroll
        for (int c = 0; c < 10; ++c) {
            atomicAdd(&total_l[c], cq[c]);
            atomicAdd(&S_l[am * 10 + c], cq[c]);
        }
    }
    __syncthreads();
    if (tid == 0) atomicAdd(&acc_g[0], lp_acc);
    if (tid < 100) {
        // tid = i*10 + c
        centers_g[bl * 100 + tid] = (total_l[tid % 10] - S_l[tid]) * 0.01f;
    }
}

// ---------------- kernel 3: cross-entropy over l axis ----------------
__global__ void k_ce(const float* __restrict__ mu_g, float* __restrict__ acc_g) {
    int bid = blockIdx.x;     // 800 = (b,u)
    int b = bid / 100;
    int u = bid % 100;
    int lane = threadIdx.x;   // 64
    float v[4];
    #pragma unroll
    for (int t = 0; t < 4; ++t) {
        int l = lane + t * 64;
        v[t] = (l < LK) ? mu_g[(b * LK + l) * 100 + u] : -3.4e38f;
    }
    float m = fmaxf(fmaxf(v[0], v[1]), fmaxf(v[2], v[3]));
    for (int o = 32; o > 0; o >>= 1) m = fmaxf(m, __shfl_xor(m, o, 64));
    float se = 0.f;
    #pragma unroll
    for (int t = 0; t < 4; ++t) {
        int l = lane + t * 64;
        if (l < LK) se += expf(v[t] - m);
    }
    for (int o = 32; o > 0; o >>= 1) se += __shfl_xor(se, o, 64);
    float lse = m + logf(se);
    float dot = 0.f;
    #pragma unroll
    for (int t = 0; t < 4; ++t) {
        int l = lane + t * 64;
        if (l < LK) dot += v[t] * (v[t] - lse);
    }
    for (int o = 32; o > 0; o >>= 1) dot += __shfl_xor(dot, o, 64);
    if (lane == 0) atomicAdd(&acc_g[1], -dot * (1.f / 800.f));
}

// ---------------- kernel 4: fused proj_back(gelu) + reshape-sum over clusters ----------------
__global__ void k_ccs(const float* __restrict__ centers_g,
                      const float* __restrict__ Wp, const float* __restrict__ bp,
                      float* __restrict__ ccs) {
    int tid = blockIdx.x * 256 + threadIdx.x;
    if (tid >= KP_TOT) return;
    int k2d2 = tid % (LK * DK);
    int bh = tid / (LK * DK);
    float s = 0.f;
    #pragma unroll
    for (int i2 = 0; i2 < 10; ++i2) {
        int t2 = bh * 145920 + i2 * 14592 + k2d2;   // flat index into cc [10,8,228,512]
        int i = t2 / 933888;
        int r1 = t2 % 933888;
        int bs = r1 / 116736;
        int r2 = r1 % 116736;
        int ls = r2 / 512;
        int mm = r2 % 512;
        const float* cen = centers_g + (bs * LK + ls) * 100 + i * 10;
        float val = bp[mm];
        #pragma unroll
        for (int c = 0; c < 10; ++c)
            val = fmaf(cen[c], Wp[c * 512 + mm], val);
        s += gelu_f(val);
    }
    ccs[tid] = s;
}

// ---------------- kernel 5: flash attention (228 keys) ----------------
#define KCH 57
__global__ __launch_bounds__(256) void k_attn(
        const float* __restrict__ Q, const float* __restrict__ ccs,
        const float* __restrict__ Vp, float* __restrict__ outp) {
    __shared__ alignas(16) float Kl[KCH * DK];
    __shared__ alignas(16) float Vl[KCH * DK];
    int tid = threadIdx.x;
    int bid = blockIdx.x;       // 512
    int b = bid >> 6;
    int h = (bid >> 3) & 7;
    int qt = bid & 7;
    int q_idx = qt * 256 + tid;

    const float4* Qv = (const float4*)(Q + ((size_t)(b * 8 + h) * 2048 + q_idx) * 64);
    float4 q4[16];
    #pragma unroll
    for (int t = 0; t < 16; ++t) q4[t] = Qv[t];

    float o[64];
    #pragma unroll
    for (int d = 0; d < 64; ++d) o[d] = 0.f;
    float mmax = -3.4e38f, lsum = 0.f;

    int kvbase = (b * 8 + h) * LK * DK;
    for (int kc = 0; kc < LK; kc += KCH) {
        const float4* Ks = (const float4*)(ccs + kvbase + kc * DK);
        const float4* Vs = (const float4*)(Vp + kvbase + kc * DK);
        for (int s = tid; s < KCH * 16; s += 256) {
            ((float4*)Kl)[s] = Ks[s];
            ((float4*)Vl)[s] = Vs[s];
        }
        __syncthreads();
        for (int k = 0; k < KCH; ++k) {
            const float4* kr = (const float4*)&Kl[k * 64];
            float s = 0.f;
            #pragma unroll
            for (int t = 0; t < 16; ++t) {
                float4 kv = kr[t];
                s = fmaf(q4[t].x, kv.x, s);
                s = fmaf(q4[t].y, kv.y, s);
                s = fmaf(q4[t].z, kv.z, s);
                s = fmaf(q4[t].w, kv.w, s);
            }
            s *= 0.125f;
            if (s > mmax) {
                float a = __expf(mmax - s);
                lsum *= a;
                #pragma unroll
                for (int d = 0; d < 64; ++d) o[d] *= a;
                mmax = s;
            }
            float p = __expf(s - mmax);
            lsum += p;
            const float4* vr = (const float4*)&Vl[k * 64];
            #pragma unroll
            for (int t = 0; t < 16; ++t) {
                float4 vv = vr[t];
                o[t * 4 + 0] = fmaf(p, vv.x, o[t * 4 + 0]);
                o[t * 4 + 1] = fmaf(p, vv.y, o[t * 4 + 1]);
                o[t * 4 + 2] = fmaf(p, vv.z, o[t * 4 + 2]);
                o[t * 4 + 3] = fmaf(p, vv.w, o[t * 4 + 3]);
            }
        }
        __syncthreads();
    }
    float inv = 1.f / lsum;
    float4* ov = (float4*)(outp + ((size_t)(b * 8 + h) * 2048 + q_idx) * 64);
    #pragma unroll
    for (int t = 0; t < 16; ++t) {
        float4 r;
        r.x = o[t * 4 + 0] * inv;
        r.y = o[t * 4 + 1] * inv;
        r.z = o[t * 4 + 2] * inv;
        r.w = o[t * 4 + 3] * inv;
        ov[t] = r;
    }
}

// ---------------- kernel 6: final loss ----------------
__global__ void k_final(const float* __restrict__ acc_g, float* __restrict__ outp) {
    outp[8388608] = -(acc_g[0] * (1.f / (float)NROWS)) + acc_g[1];
}

extern "C" void kernel_launch(void* const* d_in, const int* in_sizes, int n_in,
                              void* d_out, int out_size, void* d_ws, size_t ws_size,
                              hipStream_t stream) {
    const float* Q   = (const float*)d_in[0];
    const float* K   = (const float*)d_in[1];
    const float* V   = (const float*)d_in[2];
    const float* Wq1 = (const float*)d_in[7];
    const float* bq1 = (const float*)d_in[8];
    const float* Wq2 = (const float*)d_in[9];
    const float* bq2 = (const float*)d_in[10];
    const float* Wp  = (const float*)d_in[11];
    const float* bp  = (const float*)d_in[12];
    float* out = (float*)d_out;

    float* ws      = (float*)d_ws;
    float* Kp      = ws;                 // 933888
    float* Vp      = ws + 933888;        // 933888
    float* mu      = ws + 1867776;       // 182400
    float* centers = ws + 2050176;       // 182400
    float* ccs     = ws + 2232576;       // 933888
    float* acc     = ws + 3166464;       // 4

    k_init<<<1, 64, 0, stream>>>(acc);
    k_pool<<<(2 * KP_TOT + 255) / 256, 256, 0, stream>>>(K, V, Kp, Vp);
    k_mlp<<<NB * LK, 256, 0, stream>>>(Kp, Wq1, bq1, Wq2, bq2, mu, centers, acc);
    k_ce<<<NB * 100, 64, 0, stream>>>(mu, acc);
    k_ccs<<<(KP_TOT + 255) / 256, 256, 0, stream>>>(centers, Wp, bp, ccs);
    k_attn<<<512, 256, 0, stream>>>(Q, ccs, Vp, out);
    k_final<<<1, 1, 0, stream>>>(acc, out);
}

// Round 2
// 532.964 us; speedup vs baseline: 1.4007x; 1.4007x over previous
//
#include <hip/hip_runtime.h>
#include <math.h>

#define NCL 10
#define DM 512
#define NH 8
#define DK 64
#define NB 8
#define SL 2048
#define LK 228
#define UF 100
#define KP_PER_B (NH*LK*DK)     // 116736
#define KP_TOT (NB*KP_PER_B)    // 933888
#define NROWS (NB*LK*UF)        // 182400

typedef __bf16 bf16_t;
typedef __attribute__((ext_vector_type(8))) __bf16 bf16x8;
typedef __attribute__((ext_vector_type(4))) float f32x4;

__device__ __forceinline__ float gelu_f(float x) {
    return 0.5f * x * (1.f + erff(x * 0.70710678118654752f));
}

// ---------------- kernel 0: zero accumulators ----------------
__global__ void k_init(float* __restrict__ acc) {
    if (threadIdx.x < 4) acc[threadIdx.x] = 0.f;
}

// ---------------- kernel 1: max-pool K and V ----------------
__global__ void k_pool(const float* __restrict__ K, const float* __restrict__ V,
                       float* __restrict__ Kp, float* __restrict__ Vp) {
    int idx = blockIdx.x * 256 + threadIdx.x;
    if (idx >= 2 * KP_TOT) return;
    const float* src = (idx < KP_TOT) ? K : V;
    float* dst = (idx < KP_TOT) ? Kp : Vp;
    int e = (idx < KP_TOT) ? idx : idx - KP_TOT;
    int b   = e / KP_PER_B;
    int off = e % KP_PER_B;
    int c  = off / LK;        // channel 0..511
    int pp = off % LK;        // pooled position 0..227
    int p0 = pp * 9 - 4;
    const float* base = src + (size_t)b * 1048576 + (size_t)c * 2048;
    float mx = -3.4e38f;
    #pragma unroll
    for (int j = 0; j < 9; ++j) {
        int p = p0 + j;
        if (p >= 0 && p < 2048) mx = fmaxf(mx, base[p]);
    }
    dst[e] = mx;
}

// ---------------- kernel 2: q-MLP (bf16 MFMA layer1) + softmax + stats + centers ----
// one block per (b,l); owns all 100 u-rows.
// LDS layout (byte offsets into smem):
//   0      XA  bf16[112][72]  (16128 B)  -- aliased by hT f32[100*40] (16000 B) after GEMM
//   16128  WB  bf16[48][72]   ( 6912 B)
//   23040  Sst bf16[512][8]   ( 8192 B)
//   31232  total_l f32[10], S_l f32[100], lp_acc f32
#define XA_STRIDE 72
__global__ __launch_bounds__(256, 4) void k_mlp(
        const float* __restrict__ Kp,
        const float* __restrict__ Wq1, const float* __restrict__ bq1,
        const float* __restrict__ Wq2, const float* __restrict__ bq2,
        float* __restrict__ mu_g, float* __restrict__ centers_g,
        float* __restrict__ acc_g) {
    __shared__ __align__(16) char smem[31680];
    bf16_t* XA  = (bf16_t*)(smem);
    bf16_t* WB  = (bf16_t*)(smem + 16128);
    bf16_t* Sst = (bf16_t*)(smem + 23040);
    float*  hT  = (float*)(smem);            // alias of XA
    float*  total_l = (float*)(smem + 31232);
    float*  S_l     = (float*)(smem + 31272);
    float*  lp_acc  = (float*)(smem + 31672);

    int tid = threadIdx.x;
    int bl = blockIdx.x;          // 0..1823
    int b = bl / LK;
    int l = bl % LK;
    int wid = tid >> 6;
    int lane = tid & 63;
    int ln = lane & 15;
    int qd = lane >> 4;

    // --- stage the <=7 nonzero Kp values per run (512 runs), bf16 ---
    for (int s = tid; s < 512 * 7; s += 256) {
        int rl = s / 7;
        int bk = s % 7 + 1;                 // source batch 1..7
        int rg = l * 512 + rl;              // global run index (per batch)
        int hh = rg / 14592;
        int rh = rg % 14592;
        int lp_ = rh >> 6;
        int dd = rh & 63;
        Sst[rl * 8 + bk] = (bf16_t)Kp[((bk * NH + hh) * LK + lp_) * DK + dd];
    }
    // zero pad rows of XA (m=100..111) and WB (n=40..47), once
    for (int s = tid; s < 12 * 64; s += 256)
        XA[(100 + (s >> 6)) * XA_STRIDE + (s & 63)] = (bf16_t)0.0f;
    for (int s = tid; s < 8 * 64; s += 256)
        WB[(40 + (s >> 6)) * XA_STRIDE + (s & 63)] = (bf16_t)0.0f;
    if (tid < NCL) total_l[tid] = 0.f;
    if (tid < NCL * NCL) S_l[tid] = 0.f;
    if (tid == 0) lp_acc[0] = 0.f;

    // tile assignment: 21 tiles (7 mt x 3 nt); wave handles tile = wid + 4*t
    f32x4 acc[6];
    #pragma unroll
    for (int t = 0; t < 6; ++t) acc[t] = (f32x4)(0.f);

    __syncthreads();

    for (int kc = 0; kc < 512; kc += 64) {
        // stage X chunk: XA[m][i] = K_unf[b,l,m, kc+i], m<100
        for (int s = tid; s < 6400; s += 256) {
            int m = s >> 6;
            int i = s & 63;
            int local = (m << 9) + kc + i;      // m*512 + col
            int rl = local / 100;
            int u = local - rl * 100;
            int j = b + u;
            XA[m * XA_STRIDE + i] = (j < 100) ? (bf16_t)0.0f : Sst[(rl << 3) + (j - 99)];
        }
        // stage W1^T chunk: WB[n][i] = Wq1[(kc+i)*40 + n]  (coalesced global reads)
        for (int f0 = tid; f0 < 2560; f0 += 256) {
            int q = f0 / 40;        // i offset 0..63
            int n = f0 - q * 40;    // 0..39
            WB[n * XA_STRIDE + q] = (bf16_t)Wq1[kc * 40 + f0];
        }
        __syncthreads();
        #pragma unroll
        for (int t = 0; t < 6; ++t) {
            int tile = wid + 4 * t;
            if (tile > 20) tile = 0;     // dup work, result discarded
            int mt = tile / 3;
            int nt = tile - mt * 3;
            #pragma unroll
            for (int ks = 0; ks < 2; ++ks) {
                bf16x8 a  = *(const bf16x8*)&XA[(mt * 16 + ln) * XA_STRIDE + ks * 32 + qd * 8];
                bf16x8 bb = *(const bf16x8*)&WB[(nt * 16 + ln) * XA_STRIDE + ks * 32 + qd * 8];
                acc[t] = __builtin_amdgcn_mfma_f32_16x16x32_bf16(a, bb, acc[t], 0, 0, 0);
            }
        }
        __syncthreads();
    }

    // write D tiles (+bias) into hT (aliases XA; all mfma reads are behind the barrier)
    #pragma unroll
    for (int t = 0; t < 6; ++t) {
        int tile = wid + 4 * t;
        if (tile > 20) continue;
        int mt = tile / 3;
        int nt = tile - mt * 3;
        int n = nt * 16 + ln;
        if (n < 40) {
            float bias = bq1[n];
            #pragma unroll
            for (int r = 0; r < 4; ++r) {
                int m = mt * 16 + qd * 4 + r;
                if (m < 100) hT[m * 40 + n] = acc[t][r] + bias;
            }
        }
    }
    __syncthreads();

    if (tid < 100) {
        int row = tid;
        float g[40];
        #pragma unroll
        for (int j = 0; j < 40; ++j)
            g[j] = gelu_f(hT[row * 40 + j]);
        float out[10];
        #pragma unroll
        for (int c = 0; c < 10; ++c) out[c] = bq2[c];
        #pragma unroll
        for (int j = 0; j < 40; ++j) {
            float gj = g[j];
            #pragma unroll
            for (int c = 0; c < 10; ++c)
                out[c] = fmaf(gj, Wq2[j * 10 + c], out[c]);
        }
        // softmax + first-occurrence argmax
        float m = out[0]; int am = 0;
        #pragma unroll
        for (int c = 1; c < 10; ++c)
            if (out[c] > m) { m = out[c]; am = c; }
        float e[10], s = 0.f;
        #pragma unroll
        for (int c = 0; c < 10; ++c) { e[c] = expf(out[c] - m); s += e[c]; }
        float inv = 1.f / s;
        float cq[10], s1 = 0.f;
        #pragma unroll
        for (int c = 0; c < 10; ++c) { cq[c] = e[c] * inv; s1 += cq[c]; }
        float mean = s1 * 0.1f;
        float var = 0.f;
        #pragma unroll
        for (int c = 0; c < 10; ++c) { float d = cq[c] - mean; var += d * d; }
        float sd = sqrtf(var / 9.f);
        float sp = log1pf(expf(sd));             // softplus(std)
        float lp = -logf(sp) - 0.91893853320467274f;  // ((x-mu)/sigma)^2 ~ 1e-16, dropped
        mu_g[bl * 100 + row] = mean;
        atomicAdd(lp_acc, lp);
        #pragma unroll
        for (int c = 0; c < 10; ++c) {
            atomicAdd(&total_l[c], cq[c]);
            atomicAdd(&S_l[am * 10 + c], cq[c]);
        }
    }
    __syncthreads();
    if (tid == 0) atomicAdd(&acc_g[0], lp_acc[0]);
    if (tid < 100) {
        // tid = i*10 + c
        centers_g[bl * 100 + tid] = (total_l[tid % 10] - S_l[tid]) * 0.01f;
    }
}

// ---------------- kernel 3: cross-entropy over l axis ----------------
__global__ void k_ce(const float* __restrict__ mu_g, float* __restrict__ acc_g) {
    int bid = blockIdx.x;     // 800 = (b,u)
    int b = bid / 100;
    int u = bid % 100;
    int lane = threadIdx.x;   // 64
    float v[4];
    #pragma unroll
    for (int t = 0; t < 4; ++t) {
        int l = lane + t * 64;
        v[t] = (l < LK) ? mu_g[(b * LK + l) * 100 + u] : -3.4e38f;
    }
    float m = fmaxf(fmaxf(v[0], v[1]), fmaxf(v[2], v[3]));
    for (int o = 32; o > 0; o >>= 1) m = fmaxf(m, __shfl_xor(m, o, 64));
    float se = 0.f;
    #pragma unroll
    for (int t = 0; t < 4; ++t) {
        int l = lane + t * 64;
        if (l < LK) se += expf(v[t] - m);
    }
    for (int o = 32; o > 0; o >>= 1) se += __shfl_xor(se, o, 64);
    float lse = m + logf(se);
    float dot = 0.f;
    #pragma unroll
    for (int t = 0; t < 4; ++t) {
        int l = lane + t * 64;
        if (l < LK) dot += v[t] * (v[t] - lse);
    }
    for (int o = 32; o > 0; o >>= 1) dot += __shfl_xor(dot, o, 64);
    if (lane == 0) atomicAdd(&acc_g[1], -dot * (1.f / 800.f));
}

// ---------------- kernel 4: fused proj_back(gelu) + reshape-sum over clusters ----------------
__global__ void k_ccs(const float* __restrict__ centers_g,
                      const float* __restrict__ Wp, const float* __restrict__ bp,
                      float* __restrict__ ccs) {
    int tid = blockIdx.x * 256 + threadIdx.x;
    if (tid >= KP_TOT) return;
    int k2d2 = tid % (LK * DK);
    int bh = tid / (LK * DK);
    float s = 0.f;
    #pragma unroll
    for (int i2 = 0; i2 < 10; ++i2) {
        int t2 = bh * 145920 + i2 * 14592 + k2d2;   // flat index into cc [10,8,228,512]
        int i = t2 / 933888;
        int r1 = t2 % 933888;
        int bs = r1 / 116736;
        int r2 = r1 % 116736;
        int ls = r2 / 512;
        int mm = r2 % 512;
        const float* cen = centers_g + (bs * LK + ls) * 100 + i * 10;
        float val = bp[mm];
        #pragma unroll
        for (int c = 0; c < 10; ++c)
            val = fmaf(cen[c], Wp[c * 512 + mm], val);
        s += gelu_f(val);
    }
    ccs[tid] = s;
}

// ---------------- kernel 5: flash attention (228 keys) ----------------
#define KCH 57
__global__ __launch_bounds__(256) void k_attn(
        const float* __restrict__ Q, const float* __restrict__ ccs,
        const float* __restrict__ Vp, float* __restrict__ outp) {
    __shared__ __align__(16) float Kl[KCH * DK];
    __shared__ __align__(16) float Vl[KCH * DK];
    int tid = threadIdx.x;
    int bid = blockIdx.x;       // 512
    int b = bid >> 6;
    int h = (bid >> 3) & 7;
    int qt = bid & 7;
    int q_idx = qt * 256 + tid;

    const float4* Qv = (const float4*)(Q + ((size_t)(b * 8 + h) * 2048 + q_idx) * 64);
    float4 q4[16];
    #pragma unroll
    for (int t = 0; t < 16; ++t) q4[t] = Qv[t];

    float o[64];
    #pragma unroll
    for (int d = 0; d < 64; ++d) o[d] = 0.f;
    float mmax = -3.4e38f, lsum = 0.f;

    int kvbase = (b * 8 + h) * LK * DK;
    for (int kc = 0; kc < LK; kc += KCH) {
        const float4* Ks = (const float4*)(ccs + kvbase + kc * DK);
        const float4* Vs = (const float4*)(Vp + kvbase + kc * DK);
        for (int s = tid; s < KCH * 16; s += 256) {
            ((float4*)Kl)[s] = Ks[s];
            ((float4*)Vl)[s] = Vs[s];
        }
        __syncthreads();
        for (int k = 0; k < KCH; ++k) {
            const float4* kr = (const float4*)&Kl[k * 64];
            float s = 0.f;
            #pragma unroll
            for (int t = 0; t < 16; ++t) {
                float4 kv = kr[t];
                s = fmaf(q4[t].x, kv.x, s);
                s = fmaf(q4[t].y, kv.y, s);
                s = fmaf(q4[t].z, kv.z, s);
                s = fmaf(q4[t].w, kv.w, s);
            }
            s *= 0.125f;
            if (s > mmax) {
                float a = __expf(mmax - s);
                lsum *= a;
                #pragma unroll
                for (int d = 0; d < 64; ++d) o[d] *= a;
                mmax = s;
            }
            float p = __expf(s - mmax);
            lsum += p;
            const float4* vr = (const float4*)&Vl[k * 64];
            #pragma unroll
            for (int t = 0; t < 16; ++t) {
                float4 vv = vr[t];
                o[t * 4 + 0] = fmaf(p, vv.x, o[t * 4 + 0]);
                o[t * 4 + 1] = fmaf(p, vv.y, o[t * 4 + 1]);
                o[t * 4 + 2] = fmaf(p, vv.z, o[t * 4 + 2]);
                o[t * 4 + 3] = fmaf(p, vv.w, o[t * 4 + 3]);
            }
        }
        __syncthreads();
    }
    float inv = 1.f / lsum;
    float4* ov = (float4*)(outp + ((size_t)(b * 8 + h) * 2048 + q_idx) * 64);
    #pragma unroll
    for (int t = 0; t < 16; ++t) {
        float4 r;
        r.x = o[t * 4 + 0] * inv;
        r.y = o[t * 4 + 1] * inv;
        r.z = o[t * 4 + 2] * inv;
        r.w = o[t * 4 + 3] * inv;
        ov[t] = r;
    }
}

// ---------------- kernel 6: final loss ----------------
__global__ void k_final(const float* __restrict__ acc_g, float* __restrict__ outp) {
    outp[8388608] = -(acc_g[0] * (1.f / (float)NROWS)) + acc_g[1];
}

extern "C" void kernel_launch(void* const* d_in, const int* in_sizes, int n_in,
                              void* d_out, int out_size, void* d_ws, size_t ws_size,
                              hipStream_t stream) {
    const float* Q   = (const float*)d_in[0];
    const float* K   = (const float*)d_in[1];
    const float* V   = (const float*)d_in[2];
    const float* Wq1 = (const float*)d_in[7];
    const float* bq1 = (const float*)d_in[8];
    const float* Wq2 = (const float*)d_in[9];
    const float* bq2 = (const float*)d_in[10];
    const float* Wp  = (const float*)d_in[11];
    const float* bp  = (const float*)d_in[12];
    float* out = (float*)d_out;

    float* ws      = (float*)d_ws;
    float* Kp      = ws;                 // 933888
    float* Vp      = ws + 933888;        // 933888
    float* mu      = ws + 1867776;       // 182400
    float* centers = ws + 2050176;       // 182400
    float* ccs     = ws + 2232576;       // 933888
    float* acc     = ws + 3166464;       // 4

    k_init<<<1, 64, 0, stream>>>(acc);
    k_pool<<<(2 * KP_TOT + 255) / 256, 256, 0, stream>>>(K, V, Kp, Vp);
    k_mlp<<<NB * LK, 256, 0, stream>>>(Kp, Wq1, bq1, Wq2, bq2, mu, centers, acc);
    k_ce<<<NB * 100, 64, 0, stream>>>(mu, acc);
    k_ccs<<<(KP_TOT + 255) / 256, 256, 0, stream>>>(centers, Wp, bp, ccs);
    k_attn<<<512, 256, 0, stream>>>(Q, ccs, Vp, out);
    k_final<<<1, 1, 0, stream>>>(acc, out);
}

// Round 3
// 415.325 us; speedup vs baseline: 1.7975x; 1.2832x over previous
//
#include <hip/hip_runtime.h>
#include <math.h>

#define NCL 10
#define DM 512
#define NH 8
#define DK 64
#define NB 8
#define SL 2048
#define LK 228
#define UF 100
#define KP_PER_B (NH*LK*DK)     // 116736
#define KP_TOT (NB*KP_PER_B)    // 933888
#define NROWS (NB*LK*UF)        // 182400

typedef __bf16 bf16_t;
typedef __attribute__((ext_vector_type(2))) __bf16 bf16x2;
typedef __attribute__((ext_vector_type(8))) __bf16 bf16x8;
typedef __attribute__((ext_vector_type(4))) float f32x4;

__device__ __forceinline__ float gelu_f(float x) {
    return 0.5f * x * (1.f + erff(x * 0.70710678118654752f));
}

// ---------------- kernel 0: zero accumulators ----------------
__global__ void k_init(float* __restrict__ acc) {
    if (threadIdx.x < 4) acc[threadIdx.x] = 0.f;
}

// ---------------- kernel 1: max-pool K and V ----------------
__global__ void k_pool(const float* __restrict__ K, const float* __restrict__ V,
                       float* __restrict__ Kp, float* __restrict__ Vp) {
    int idx = blockIdx.x * 256 + threadIdx.x;
    if (idx >= 2 * KP_TOT) return;
    const float* src = (idx < KP_TOT) ? K : V;
    float* dst = (idx < KP_TOT) ? Kp : Vp;
    int e = (idx < KP_TOT) ? idx : idx - KP_TOT;
    int b   = e / KP_PER_B;
    int off = e % KP_PER_B;
    int c  = off / LK;        // channel 0..511
    int pp = off % LK;        // pooled position 0..227
    int p0 = pp * 9 - 4;
    const float* base = src + (size_t)b * 1048576 + (size_t)c * 2048;
    float mx = -3.4e38f;
    #pragma unroll
    for (int j = 0; j < 9; ++j) {
        int p = p0 + j;
        if (p >= 0 && p < 2048) mx = fmaxf(mx, base[p]);
    }
    dst[e] = mx;
}

// ---------------- kernel 2: q-MLP (bf16 MFMA layer1) + softmax + stats + centers ----
#define XA_STRIDE 72
__global__ __launch_bounds__(256, 4) void k_mlp(
        const float* __restrict__ Kp,
        const float* __restrict__ Wq1, const float* __restrict__ bq1,
        const float* __restrict__ Wq2, const float* __restrict__ bq2,
        float* __restrict__ mu_g, float* __restrict__ centers_g,
        float* __restrict__ acc_g) {
    __shared__ __align__(16) char smem[31680];
    bf16_t* XA  = (bf16_t*)(smem);
    bf16_t* WB  = (bf16_t*)(smem + 16128);
    bf16_t* Sst = (bf16_t*)(smem + 23040);
    float*  hT  = (float*)(smem);            // alias of XA
    float*  total_l = (float*)(smem + 31232);
    float*  S_l     = (float*)(smem + 31272);
    float*  lp_acc  = (float*)(smem + 31672);

    int tid = threadIdx.x;
    int bl = blockIdx.x;          // 0..1823
    int b = bl / LK;
    int l = bl % LK;
    int wid = tid >> 6;
    int lane = tid & 63;
    int ln = lane & 15;
    int qd = lane >> 4;

    for (int s = tid; s < 512 * 7; s += 256) {
        int rl = s / 7;
        int bk = s % 7 + 1;                 // source batch 1..7
        int rg = l * 512 + rl;              // global run index (per batch)
        int hh = rg / 14592;
        int rh = rg % 14592;
        int lp_ = rh >> 6;
        int dd = rh & 63;
        Sst[rl * 8 + bk] = (bf16_t)Kp[((bk * NH + hh) * LK + lp_) * DK + dd];
    }
    for (int s = tid; s < 12 * 64; s += 256)
        XA[(100 + (s >> 6)) * XA_STRIDE + (s & 63)] = (bf16_t)0.0f;
    for (int s = tid; s < 8 * 64; s += 256)
        WB[(40 + (s >> 6)) * XA_STRIDE + (s & 63)] = (bf16_t)0.0f;
    if (tid < NCL) total_l[tid] = 0.f;
    if (tid < NCL * NCL) S_l[tid] = 0.f;
    if (tid == 0) lp_acc[0] = 0.f;

    f32x4 acc[6];
    #pragma unroll
    for (int t = 0; t < 6; ++t) acc[t] = (f32x4)(0.f);

    __syncthreads();

    for (int kc = 0; kc < 512; kc += 64) {
        for (int s = tid; s < 6400; s += 256) {
            int m = s >> 6;
            int i = s & 63;
            int local = (m << 9) + kc + i;      // m*512 + col
            int rl = local / 100;
            int u = local - rl * 100;
            int j = b + u;
            XA[m * XA_STRIDE + i] = (j < 100) ? (bf16_t)0.0f : Sst[(rl << 3) + (j - 99)];
        }
        for (int f0 = tid; f0 < 2560; f0 += 256) {
            int q = f0 / 40;        // i offset 0..63
            int n = f0 - q * 40;    // 0..39
            WB[n * XA_STRIDE + q] = (bf16_t)Wq1[kc * 40 + f0];
        }
        __syncthreads();
        #pragma unroll
        for (int t = 0; t < 6; ++t) {
            int tile = wid + 4 * t;
            if (tile > 20) tile = 0;     // dup work, result discarded
            int mt = tile / 3;
            int nt = tile - mt * 3;
            #pragma unroll
            for (int ks = 0; ks < 2; ++ks) {
                bf16x8 a  = *(const bf16x8*)&XA[(mt * 16 + ln) * XA_STRIDE + ks * 32 + qd * 8];
                bf16x8 bb = *(const bf16x8*)&WB[(nt * 16 + ln) * XA_STRIDE + ks * 32 + qd * 8];
                acc[t] = __builtin_amdgcn_mfma_f32_16x16x32_bf16(a, bb, acc[t], 0, 0, 0);
            }
        }
        __syncthreads();
    }

    #pragma unroll
    for (int t = 0; t < 6; ++t) {
        int tile = wid + 4 * t;
        if (tile > 20) continue;
        int mt = tile / 3;
        int nt = tile - mt * 3;
        int n = nt * 16 + ln;
        if (n < 40) {
            float bias = bq1[n];
            #pragma unroll
            for (int r = 0; r < 4; ++r) {
                int m = mt * 16 + qd * 4 + r;
                if (m < 100) hT[m * 40 + n] = acc[t][r] + bias;
            }
        }
    }
    __syncthreads();

    if (tid < 100) {
        int row = tid;
        float g[40];
        #pragma unroll
        for (int j = 0; j < 40; ++j)
            g[j] = gelu_f(hT[row * 40 + j]);
        float out[10];
        #pragma unroll
        for (int c = 0; c < 10; ++c) out[c] = bq2[c];
        #pragma unroll
        for (int j = 0; j < 40; ++j) {
            float gj = g[j];
            #pragma unroll
            for (int c = 0; c < 10; ++c)
                out[c] = fmaf(gj, Wq2[j * 10 + c], out[c]);
        }
        float m = out[0]; int am = 0;
        #pragma unroll
        for (int c = 1; c < 10; ++c)
            if (out[c] > m) { m = out[c]; am = c; }
        float e[10], s = 0.f;
        #pragma unroll
        for (int c = 0; c < 10; ++c) { e[c] = expf(out[c] - m); s += e[c]; }
        float inv = 1.f / s;
        float cq[10], s1 = 0.f;
        #pragma unroll
        for (int c = 0; c < 10; ++c) { cq[c] = e[c] * inv; s1 += cq[c]; }
        float mean = s1 * 0.1f;
        float var = 0.f;
        #pragma unroll
        for (int c = 0; c < 10; ++c) { float d = cq[c] - mean; var += d * d; }
        float sd = sqrtf(var / 9.f);
        float sp = log1pf(expf(sd));
        float lp = -logf(sp) - 0.91893853320467274f;
        mu_g[bl * 100 + row] = mean;
        atomicAdd(lp_acc, lp);
        #pragma unroll
        for (int c = 0; c < 10; ++c) {
            atomicAdd(&total_l[c], cq[c]);
            atomicAdd(&S_l[am * 10 + c], cq[c]);
        }
    }
    __syncthreads();
    if (tid == 0) atomicAdd(&acc_g[0], lp_acc[0]);
    if (tid < 100) {
        centers_g[bl * 100 + tid] = (total_l[tid % 10] - S_l[tid]) * 0.01f;
    }
}

// ---------------- kernel 3: cross-entropy over l axis ----------------
__global__ void k_ce(const float* __restrict__ mu_g, float* __restrict__ acc_g) {
    int bid = blockIdx.x;     // 800 = (b,u)
    int b = bid / 100;
    int u = bid % 100;
    int lane = threadIdx.x;   // 64
    float v[4];
    #pragma unroll
    for (int t = 0; t < 4; ++t) {
        int l = lane + t * 64;
        v[t] = (l < LK) ? mu_g[(b * LK + l) * 100 + u] : -3.4e38f;
    }
    float m = fmaxf(fmaxf(v[0], v[1]), fmaxf(v[2], v[3]));
    for (int o = 32; o > 0; o >>= 1) m = fmaxf(m, __shfl_xor(m, o, 64));
    float se = 0.f;
    #pragma unroll
    for (int t = 0; t < 4; ++t) {
        int l = lane + t * 64;
        if (l < LK) se += expf(v[t] - m);
    }
    for (int o = 32; o > 0; o >>= 1) se += __shfl_xor(se, o, 64);
    float lse = m + logf(se);
    float dot = 0.f;
    #pragma unroll
    for (int t = 0; t < 4; ++t) {
        int l = lane + t * 64;
        if (l < LK) dot += v[t] * (v[t] - lse);
    }
    for (int o = 32; o > 0; o >>= 1) dot += __shfl_xor(dot, o, 64);
    if (lane == 0) atomicAdd(&acc_g[1], -dot * (1.f / 800.f));
}

// ---------------- kernel 4: fused proj_back(gelu) + reshape-sum over clusters ----------------
__global__ void k_ccs(const float* __restrict__ centers_g,
                      const float* __restrict__ Wp, const float* __restrict__ bp,
                      float* __restrict__ ccs) {
    int tid = blockIdx.x * 256 + threadIdx.x;
    if (tid >= KP_TOT) return;
    int k2d2 = tid % (LK * DK);
    int bh = tid / (LK * DK);
    float s = 0.f;
    #pragma unroll
    for (int i2 = 0; i2 < 10; ++i2) {
        int t2 = bh * 145920 + i2 * 14592 + k2d2;   // flat index into cc [10,8,228,512]
        int i = t2 / 933888;
        int r1 = t2 % 933888;
        int bs = r1 / 116736;
        int r2 = r1 % 116736;
        int ls = r2 / 512;
        int mm = r2 % 512;
        const float* cen = centers_g + (bs * LK + ls) * 100 + i * 10;
        float val = bp[mm];
        #pragma unroll
        for (int c = 0; c < 10; ++c)
            val = fmaf(cen[c], Wp[c * 512 + mm], val);
        s += gelu_f(val);
    }
    ccs[tid] = s;
}

// ---------------- kernel 5: MFMA flash attention (228 keys, chunks of 64) ----------------
// block = 256 threads (4 waves), 128 queries; wave w owns queries w*32..w*32+31.
// LDS: Kl bf16[64][72] (9216) | Vt bf16[64][72] dv-major (9216) | Pl bf16[128][72] (18432)
// Pl doubles as Q staging at kernel start.
#define QT 128
__global__ __launch_bounds__(256, 3) void k_attn(
        const float* __restrict__ Q, const float* __restrict__ ccs,
        const float* __restrict__ Vp, float* __restrict__ outp) {
    __shared__ __align__(16) char smem[36864];
    bf16_t* Kl = (bf16_t*)(smem);
    bf16_t* Vt = (bf16_t*)(smem + 9216);
    bf16_t* Pl = (bf16_t*)(smem + 18432);

    int tid = threadIdx.x;
    int wid = tid >> 6;
    int lane = tid & 63;
    int ln = lane & 15;
    int qd = lane >> 4;
    int bid = blockIdx.x;        // 1024
    int bh = bid >> 4;           // b*8+h
    int qt = bid & 15;
    int qbase = qt * QT;

    const float* Qbh = Q + (size_t)bh * SL * DK;
    const float* Kbh = ccs + (size_t)bh * LK * DK;
    const float* Vbh = Vp + (size_t)bh * LK * DK;

    // ---- stage Q tile (128x64 fp32 -> bf16, stride 72) into Pl region
    for (int s = tid; s < QT * 32; s += 256) {
        int r = s >> 5;
        int c2 = s & 31;
        float2 v = *(const float2*)&Qbh[(size_t)(qbase + r) * DK + c2 * 2];
        *(bf16x2*)&Pl[r * 72 + c2 * 2] = (bf16x2){(bf16_t)v.x, (bf16_t)v.y};
    }
    __syncthreads();
    bf16x8 qf[2][2];
    #pragma unroll
    for (int mt = 0; mt < 2; ++mt)
        #pragma unroll
        for (int ks = 0; ks < 2; ++ks)
            qf[mt][ks] = *(const bf16x8*)&Pl[(wid * 32 + mt * 16 + ln) * 72 + ks * 32 + qd * 8];

    f32x4 acc_o[2][4];
    float mrow[2][4], lrow[2][4];
    #pragma unroll
    for (int mt = 0; mt < 2; ++mt)
        #pragma unroll
        for (int t = 0; t < 4; ++t) {
            acc_o[mt][t] = (f32x4)(0.f);
            mrow[mt][t] = -3.0e38f;
            lrow[mt][t] = 0.f;
        }

    for (int ch = 0; ch < 4; ++ch) {
        int k0 = ch * 64;
        __syncthreads();     // prior chunk's Kl/Vt reads complete
        // stage K chunk (64 keys x 64 d), zero-pad keys >= 228
        for (int s = tid; s < 64 * 32; s += 256) {
            int kk = s >> 5;
            int c2 = s & 31;
            int key = k0 + kk;
            float2 v = (key < LK) ? *(const float2*)&Kbh[(size_t)key * DK + c2 * 2]
                                  : make_float2(0.f, 0.f);
            *(bf16x2*)&Kl[kk * 72 + c2 * 2] = (bf16x2){(bf16_t)v.x, (bf16_t)v.y};
        }
        // stage V chunk transposed: Vt[dv][kk]
        for (int s = tid; s < 64 * 16; s += 256) {
            int kk = s >> 4;
            int c4 = s & 15;
            int key = k0 + kk;
            float4 v = (key < LK) ? *(const float4*)&Vbh[(size_t)key * DK + c4 * 4]
                                  : make_float4(0.f, 0.f, 0.f, 0.f);
            Vt[(c4 * 4 + 0) * 72 + kk] = (bf16_t)v.x;
            Vt[(c4 * 4 + 1) * 72 + kk] = (bf16_t)v.y;
            Vt[(c4 * 4 + 2) * 72 + kk] = (bf16_t)v.z;
            Vt[(c4 * 4 + 3) * 72 + kk] = (bf16_t)v.w;
        }
        __syncthreads();

        // scores: S[q][key] for this chunk
        f32x4 accs[2][4];
        #pragma unroll
        for (int mt = 0; mt < 2; ++mt)
            #pragma unroll
            for (int nt = 0; nt < 4; ++nt) accs[mt][nt] = (f32x4)(0.f);
        #pragma unroll
        for (int ks = 0; ks < 2; ++ks) {
            #pragma unroll
            for (int nt = 0; nt < 4; ++nt) {
                bf16x8 bf = *(const bf16x8*)&Kl[(nt * 16 + ln) * 72 + ks * 32 + qd * 8];
                #pragma unroll
                for (int mt = 0; mt < 2; ++mt)
                    accs[mt][nt] = __builtin_amdgcn_mfma_f32_16x16x32_bf16(qf[mt][ks], bf, accs[mt][nt], 0, 0, 0);
            }
        }

        // online softmax per row; write P (bf16) to own Pl rows
        #pragma unroll
        for (int mt = 0; mt < 2; ++mt) {
            #pragma unroll
            for (int r = 0; r < 4; ++r) {
                float sv[4];
                #pragma unroll
                for (int nt = 0; nt < 4; ++nt) {
                    float s = accs[mt][nt][r] * 0.125f;
                    int key = k0 + nt * 16 + ln;
                    sv[nt] = (key < LK) ? s : -3.0e38f;
                }
                float rmax = fmaxf(fmaxf(sv[0], sv[1]), fmaxf(sv[2], sv[3]));
                #pragma unroll
                for (int o = 1; o < 16; o <<= 1)
                    rmax = fmaxf(rmax, __shfl_xor(rmax, o, 64));
                float mold = mrow[mt][r];
                float mnew = fmaxf(mold, rmax);
                float alpha = __expf(mold - mnew);
                float p[4], psum = 0.f;
                #pragma unroll
                for (int nt = 0; nt < 4; ++nt) {
                    p[nt] = __expf(sv[nt] - mnew);
                    psum += p[nt];
                }
                #pragma unroll
                for (int o = 1; o < 16; o <<= 1)
                    psum += __shfl_xor(psum, o, 64);
                lrow[mt][r] = lrow[mt][r] * alpha + psum;
                mrow[mt][r] = mnew;
                #pragma unroll
                for (int ntv = 0; ntv < 4; ++ntv)
                    acc_o[mt][ntv][r] *= alpha;
                int prow = (wid * 32 + mt * 16 + qd * 4 + r) * 72;
                #pragma unroll
                for (int nt = 0; nt < 4; ++nt)
                    Pl[prow + nt * 16 + ln] = (bf16_t)p[nt];
            }
        }

        // PV: O += P * V   (reads own Pl rows; Vt shared, staged behind barrier)
        #pragma unroll
        for (int ks = 0; ks < 2; ++ks) {
            bf16x8 pa[2];
            #pragma unroll
            for (int mt = 0; mt < 2; ++mt)
                pa[mt] = *(const bf16x8*)&Pl[(wid * 32 + mt * 16 + ln) * 72 + ks * 32 + qd * 8];
            #pragma unroll
            for (int ntv = 0; ntv < 4; ++ntv) {
                bf16x8 vb = *(const bf16x8*)&Vt[(ntv * 16 + ln) * 72 + ks * 32 + qd * 8];
                #pragma unroll
                for (int mt = 0; mt < 2; ++mt)
                    acc_o[mt][ntv] = __builtin_amdgcn_mfma_f32_16x16x32_bf16(pa[mt], vb, acc_o[mt][ntv], 0, 0, 0);
            }
        }
    }

    // epilogue: normalize and store
    #pragma unroll
    for (int mt = 0; mt < 2; ++mt) {
        #pragma unroll
        for (int r = 0; r < 4; ++r) {
            float inv = 1.f / lrow[mt][r];
            int q_idx = qbase + wid * 32 + mt * 16 + qd * 4 + r;
            float* orow = outp + ((size_t)bh * SL + q_idx) * DK;
            #pragma unroll
            for (int ntv = 0; ntv < 4; ++ntv)
                orow[ntv * 16 + ln] = acc_o[mt][ntv][r] * inv;
        }
    }
}

// ---------------- kernel 6: final loss ----------------
__global__ void k_final(const float* __restrict__ acc_g, float* __restrict__ outp) {
    outp[8388608] = -(acc_g[0] * (1.f / (float)NROWS)) + acc_g[1];
}

extern "C" void kernel_launch(void* const* d_in, const int* in_sizes, int n_in,
                              void* d_out, int out_size, void* d_ws, size_t ws_size,
                              hipStream_t stream) {
    const float* Q   = (const float*)d_in[0];
    const float* K   = (const float*)d_in[1];
    const float* V   = (const float*)d_in[2];
    const float* Wq1 = (const float*)d_in[7];
    const float* bq1 = (const float*)d_in[8];
    const float* Wq2 = (const float*)d_in[9];
    const float* bq2 = (const float*)d_in[10];
    const float* Wp  = (const float*)d_in[11];
    const float* bp  = (const float*)d_in[12];
    float* out = (float*)d_out;

    float* ws      = (float*)d_ws;
    float* Kp      = ws;                 // 933888
    float* Vp      = ws + 933888;        // 933888
    float* mu      = ws + 1867776;       // 182400
    float* centers = ws + 2050176;       // 182400
    float* ccs     = ws + 2232576;       // 933888
    float* acc     = ws + 3166464;       // 4

    k_init<<<1, 64, 0, stream>>>(acc);
    k_pool<<<(2 * KP_TOT + 255) / 256, 256, 0, stream>>>(K, V, Kp, Vp);
    k_mlp<<<NB * LK, 256, 0, stream>>>(Kp, Wq1, bq1, Wq2, bq2, mu, centers, acc);
    k_ce<<<NB * 100, 64, 0, stream>>>(mu, acc);
    k_ccs<<<(KP_TOT + 255) / 256, 256, 0, stream>>>(centers, Wp, bp, ccs);
    k_attn<<<NB * NH * (SL / QT), 256, 0, stream>>>(Q, ccs, Vp, out);
    k_final<<<1, 1, 0, stream>>>(acc, out);
}